// Round 4
// baseline (248.075 us; speedup 1.0000x reference)
//
#include <hip/hip_runtime.h>

#define T_DIM 2048
#define B_DIM 16
#define C_DIM 512
#define NW 56            // H*K

typedef __attribute__((ext_vector_type(8))) short short8;
typedef __attribute__((ext_vector_type(4))) float floatx4;

static __device__ __forceinline__ unsigned short f2bf(float x) {
    union { float f; unsigned u; } v; v.f = x;
    return (unsigned short)((v.u + 0x7FFFu + ((v.u >> 16) & 1u)) >> 16);  // RNE
}

// ---------------------------------------------------------------------------
// Pre-kernel: pack W (512x56 fp32) into bf16 MFMA B-fragments, lane order:
// Bg[(ks*4+nt)*64 + l][j] = W[k = ks*32+(l>>4)*8+j][n = nt*16+(l&15)], 0-pad n>=56.
// 64 KB total -> L2-resident, broadcast to all fused blocks.
// ---------------------------------------------------------------------------
__global__ __launch_bounds__(256)
void pack_w(const float* __restrict__ W, short8* __restrict__ Bg) {
    const int g  = blockIdx.x * 256 + threadIdx.x;   // 0..4095
    const int ks = g >> 8;
    const int nt = (g >> 6) & 3;
    const int l  = g & 63;
    const int n  = nt * 16 + (l & 15);
    const int k0 = ks * 32 + ((l >> 4) & 3) * 8;
    short8 o;
#pragma unroll
    for (int j = 0; j < 8; ++j) {
        const float v = (n < NW) ? W[(size_t)(k0 + j) * NW + n] : 0.f;
        o[j] = (short)f2bf(v);
    }
    Bg[g] = o;
}

// ---------------------------------------------------------------------------
// Fused kernel: block = 16 t x 1 b, 4 waves.
//  GEMM: 16-row logit tile via bf16 MFMA; A frags staged through LDS (16 KB,
//  conflict-free b128), B frags from registers (L2-hot packed Bg).
//  Softmax: logits -> L (LDS) -> per-(row,head) softmax -> wt (LDS).
//  Conv: lane l owns outputs c=8l..8l+8 <=> window floats [56l,56l+56) =
//  14 aligned float4 read DIRECTLY from global (window rows t-3..t+3,
//  zero outside [0,T)). No x LDS staging, no bank conflicts, fp32 precision.
//  LDS total 24128 B -> 6 blocks/CU; launch_bounds(256,4) caps VGPR at 128.
// ---------------------------------------------------------------------------
__global__ __launch_bounds__(256, 4)
void fused_kernel(const float* __restrict__ x, const float* __restrict__ q,
                  const short8* __restrict__ Bg, float* __restrict__ out) {
    __shared__ __align__(16) short8 A8[16 * 64];   // 16384 B  A fragments
    __shared__ float L[16 * 65];                   //  4160 B  logit tile
    __shared__ float wt[16 * NW];                  //  3584 B  softmaxed weights

    const int tid  = threadIdx.x;
    const int lane = tid & 63;
    const int wv   = tid >> 6;                 // wave id = ntile
    const int b    = blockIdx.x & 15;
    const int t0   = (blockIdx.x >> 4) * 16;

    // ---- B-frag loads (coalesced 16 B/lane, L2-hot)
    short8 bfr[16];
#pragma unroll
    for (int ks = 0; ks < 16; ++ks)
        bfr[ks] = Bg[(ks * 4 + wv) * 64 + lane];

    // ---- q -> A frags in LDS: A8[ks*64+l] = row (l&15), k = ks*32+(l>>4)*8..+8
    const int rq = lane & 15;
    const int qq = lane >> 4;
    const float* qrow = q + ((size_t)(t0 + rq) * B_DIM + b) * C_DIM + qq * 8;
#pragma unroll
    for (int s = 0; s < 4; ++s) {
        const int ks = wv + s * 4;
        const float4 v0 = *(const float4*)(qrow + ks * 32);
        const float4 v1 = *(const float4*)(qrow + ks * 32 + 4);
        short8 o;
        o[0] = (short)f2bf(v0.x); o[1] = (short)f2bf(v0.y);
        o[2] = (short)f2bf(v0.z); o[3] = (short)f2bf(v0.w);
        o[4] = (short)f2bf(v1.x); o[5] = (short)f2bf(v1.y);
        o[6] = (short)f2bf(v1.z); o[7] = (short)f2bf(v1.w);
        A8[ks * 64 + lane] = o;
    }
    __syncthreads();

    // ---- GEMM: wave wv owns n-tile wv (16 n), rows 0..15 = tt
    floatx4 acc = (floatx4){0.f, 0.f, 0.f, 0.f};
#pragma unroll
    for (int ks = 0; ks < 16; ++ks)
        acc = __builtin_amdgcn_mfma_f32_16x16x32_bf16(A8[ks * 64 + lane], bfr[ks],
                                                      acc, 0, 0, 0);

    // ---- logits -> L; D layout: row = (lane>>4)*4 + r, col = lane&15
    const int m = lane & 15, quad = lane >> 4;
#pragma unroll
    for (int r = 0; r < 4; ++r)
        L[(quad * 4 + r) * 65 + wv * 16 + m] = acc[r];
    __syncthreads();

    // ---- softmax over groups of 7: 16 rows x 8 heads = 128 tasks -> wt
    if (tid < 128) {
        const int row = tid >> 3, h = tid & 7;
        const float* Lp = &L[row * 65 + h * 7];
        float mx = Lp[0];
#pragma unroll
        for (int k = 1; k < 7; ++k) mx = fmaxf(mx, Lp[k]);
        float e[7], sm = 0.f;
#pragma unroll
        for (int k = 0; k < 7; ++k) { e[k] = __expf(Lp[k] - mx); sm += e[k]; }
        const float inv = 1.0f / sm;
#pragma unroll
        for (int k = 0; k < 7; ++k) wt[row * NW + h * 7 + k] = e[k] * inv;
    }
    __syncthreads();

    // ---- conv: window float f = 56*lane + j*7 + k, row d = f>>9, col = f&511
    const int f0 = lane * 56;
    const int hh = lane >> 3;
#pragma unroll
    for (int s = 0; s < 4; ++s) {
        const int tt = wv * 4 + s;
        const int tb = t0 + tt - 3;
        float xf[56];
#pragma unroll
        for (int i = 0; i < 14; ++i) {
            const int f = f0 + i * 4;
            const int d = f >> 9;
            const int c = f & 511;
            const int tp = tb + d;
            float4 v = make_float4(0.f, 0.f, 0.f, 0.f);
            if ((unsigned)tp < (unsigned)T_DIM)
                v = *(const float4*)(x + ((size_t)tp * B_DIM + b) * C_DIM + c);
            *(float4*)(&xf[i * 4]) = v;
        }
        const float* wp = &wt[tt * NW + hh * 7];
        float w[7];
#pragma unroll
        for (int k = 0; k < 7; ++k) w[k] = wp[k];
        float a8[8];
#pragma unroll
        for (int r = 0; r < 8; ++r) {
            float sacc = xf[r * 7] * w[0];
#pragma unroll
            for (int k = 1; k < 7; ++k) sacc = fmaf(w[k], xf[r * 7 + k], sacc);
            a8[r] = sacc;
        }
        float* orow = out + ((size_t)(t0 + tt) * B_DIM + b) * C_DIM + lane * 8;
        *(float4*)(orow)     = make_float4(a8[0], a8[1], a8[2], a8[3]);
        *(float4*)(orow + 4) = make_float4(a8[4], a8[5], a8[6], a8[7]);
    }
}

extern "C" void kernel_launch(void* const* d_in, const int* in_sizes, int n_in,
                              void* d_out, int out_size, void* d_ws, size_t ws_size,
                              hipStream_t stream) {
    const float* x = (const float*)d_in[0];
    const float* q = (const float*)d_in[1];
    const float* W = (const float*)d_in[2];
    float* out = (float*)d_out;
    short8* Bg = (short8*)d_ws;   // 64 KB packed bf16 B-fragments

    pack_w<<<16, 256, 0, stream>>>(W, Bg);
    fused_kernel<<<(T_DIM / 16) * B_DIM, 256, 0, stream>>>(x, q, Bg, out);
}